// Round 3
// baseline (395.279 us; speedup 1.0000x reference)
//
#include <hip/hip_runtime.h>
#include <hip/hip_bf16.h>

typedef __bf16 bf16;
typedef __bf16 bf16x8 __attribute__((ext_vector_type(8)));
typedef float floatx4 __attribute__((ext_vector_type(4)));

#define B_ROWS 4096
#define IN_DIM 512
#define DIM 1024
#define NG 10

__device__ __forceinline__ float geluf(float x) {
    return 0.5f * x * (1.0f + erff(x * 0.70710678118654752f));
}

// ---------------------------------------------------------------------------
// prep: ng[row] = bf16( mu[g] + (|sigma[g]|+eps) * z[row] ); histogram counts
// all inputs fp32; ng stored bf16 (it is GEMM1's A operand)
// ---------------------------------------------------------------------------
__global__ void prep_kernel(const int* __restrict__ genre,
                            const float* __restrict__ z,
                            const float* __restrict__ mu_t,
                            const float* __restrict__ sg_t,
                            bf16* __restrict__ ng,
                            int* __restrict__ counts) {
    const int row = blockIdx.x;
    const int g = genre[row];
    const int c0 = threadIdx.x * 8;
    const float* zp = z + (size_t)row * IN_DIM + c0;
    const float* mp = mu_t + (size_t)g * IN_DIM + c0;
    const float* sp = sg_t + (size_t)g * IN_DIM + c0;
    floatx4 z0 = *(const floatx4*)zp, z1 = *(const floatx4*)(zp + 4);
    floatx4 m0 = *(const floatx4*)mp, m1 = *(const floatx4*)(mp + 4);
    floatx4 s0 = *(const floatx4*)sp, s1 = *(const floatx4*)(sp + 4);
    bf16x8 o;
#pragma unroll
    for (int i = 0; i < 4; i++) {
        o[i] = (bf16)(m0[i] + (fabsf(s0[i]) + 1e-8f) * z0[i]);
        o[i + 4] = (bf16)(m1[i] + (fabsf(s1[i]) + 1e-8f) * z1[i]);
    }
    *(bf16x8*)(ng + (size_t)row * IN_DIM + c0) = o;
    if (threadIdx.x == 0) atomicAdd(&counts[g], 1);
}

__global__ void scan_kernel(const int* __restrict__ counts,
                            int* __restrict__ offsets,
                            int* __restrict__ cursors) {
    if (threadIdx.x == 0 && blockIdx.x == 0) {
        int acc = 0;
        for (int g = 0; g < NG; g++) {
            offsets[g] = acc;
            cursors[g] = acc;
            acc += counts[g];
        }
        offsets[NG] = acc;
    }
}

__global__ void scatter_kernel(const int* __restrict__ genre,
                               int* __restrict__ cursors,
                               int* __restrict__ row_ids) {
    int row = blockIdx.x * blockDim.x + threadIdx.x;
    if (row < B_ROWS) {
        int g = genre[row];
        int pos = atomicAdd(&cursors[g], 1);
        row_ids[pos] = row;
    }
}

// ---------------------------------------------------------------------------
// GEMM: C = act(A @ B + bias).  A [M][K] bf16 row-major, B [K][N] fp32
// row-major (converted to bf16 at staging), bias fp32, C dtype = CT.
// B transposed on-the-fly into LDS tile Bs [n][k] with k-block XOR swizzle
// (kblk ^ (n>>3)&7): scalar transpose writes spread across bank groups
// (2-way = free per m136) while fragment reads stay single ds_read_b128.
// EXPERT: grid.z = genre; rows are bucket positions [0,count) at offsets[g].
// ---------------------------------------------------------------------------
template <bool EXPERT, bool GATHER_A, bool SCATTER_C, bool GELU, typename CT>
__global__ __launch_bounds__(256, 2) void gemm_kernel(
    const bf16* __restrict__ A, const float* __restrict__ Bmat,
    const float* __restrict__ bias, CT* __restrict__ Cmat,
    int M, int N, int K,
    const int* __restrict__ row_ids, const int* __restrict__ offsets,
    const int* __restrict__ counts) {
    int off = 0, cnt = M;
    if (EXPERT) {
        const int g = blockIdx.z;
        cnt = counts[g];
        if ((int)blockIdx.y * 128 >= cnt) return;
        off = offsets[g];
        Bmat += (size_t)g * K * N;
        bias += (size_t)g * N;
    }
    const int m_start = blockIdx.y * 128;
    const int n0 = blockIdx.x * 128;

    constexpr int BK = 64;
    constexpr int LK = BK + 8;  // 2-way bank alias only (free per m136)
    __shared__ bf16 As[128 * LK];
    __shared__ bf16 Bs[128 * LK];

    const int tid = threadIdx.x;
    const int lane = tid & 63;
    const int wave = tid >> 6;
    const int wr = (wave >> 1) * 64;
    const int wc = (wave & 1) * 64;
    const int quad = lane >> 4;
    const int l16 = lane & 15;

    // A staging map: flat octet f = tid + i*256 -> row f>>3, col (f&7)*8
    int a_r[4], a_c[4];
    size_t a_src[4];
#pragma unroll
    for (int i = 0; i < 4; i++) {
        int f = tid + i * 256;
        int r = f >> 3;
        int c = (f & 7) * 8;
        a_r[i] = r;
        a_c[i] = c;
        int p = m_start + r;
        size_t srow;
        if (EXPERT) {
            int pp = off + min(p, cnt - 1);
            srow = GATHER_A ? (size_t)row_ids[pp] : (size_t)pp;
        } else {
            srow = (size_t)p;
        }
        a_src[i] = srow * (size_t)K + c;
    }
    // B staging map: f = tid + i*256 -> k_local f>>4, n-octet (f&15)*8
    int b_k[4], b_m[4];
#pragma unroll
    for (int i = 0; i < 4; i++) {
        int f = tid + i * 256;
        b_k[i] = f >> 4;
        b_m[i] = f & 15;
    }

    floatx4 acc[4][4];
#pragma unroll
    for (int i = 0; i < 4; i++)
#pragma unroll
        for (int j = 0; j < 4; j++)
#pragma unroll
            for (int r = 0; r < 4; r++) acc[i][j][r] = 0.0f;

    const int nK = K / BK;
    for (int kt = 0; kt < nK; kt++) {
        const int kbase = kt * BK;
#pragma unroll
        for (int i = 0; i < 4; i++) {
            bf16x8 va = *(const bf16x8*)(A + a_src[i] + kbase);
            *(bf16x8*)(As + a_r[i] * LK + a_c[i]) = va;
            // B: load 8 n-contiguous fp32, cvt, scatter into Bs[n][k] swizzled
            const int kl = b_k[i];
            const int m = b_m[i];
            const float* brow =
                Bmat + (size_t)(kbase + kl) * N + n0 + m * 8;
            floatx4 v0 = *(const floatx4*)brow;
            floatx4 v1 = *(const floatx4*)(brow + 4);
            const int swk = (((kl >> 3) ^ (m & 7)) << 3) + (kl & 7);
            bf16* bs = Bs + m * 8 * LK + swk;
#pragma unroll
            for (int j = 0; j < 4; j++) {
                bs[j * LK] = (bf16)v0[j];
                bs[(j + 4) * LK] = (bf16)v1[j];
            }
        }
        __syncthreads();
#pragma unroll
        for (int ks = 0; ks < BK / 32; ks++) {
            bf16x8 af[4], bfr[4];
#pragma unroll
            for (int i = 0; i < 4; i++)
                af[i] = *(const bf16x8*)(As + (wr + i * 16 + l16) * LK + ks * 32 +
                                         quad * 8);
#pragma unroll
            for (int j = 0; j < 4; j++) {
                const int n = wc + j * 16 + l16;
                const int kb = ks * 4 + quad;
                bfr[j] = *(const bf16x8*)(Bs + n * LK +
                                          ((kb ^ ((n >> 3) & 7)) << 3));
            }
#pragma unroll
            for (int i = 0; i < 4; i++)
#pragma unroll
                for (int j = 0; j < 4; j++)
                    acc[i][j] = __builtin_amdgcn_mfma_f32_16x16x32_bf16(
                        af[i], bfr[j], acc[i][j], 0, 0, 0);
        }
        __syncthreads();
    }

    // epilogue: C/D layout col = lane&15, row = quad*4 + reg  [m89-verified]
#pragma unroll
    for (int j = 0; j < 4; j++) {
        const int n = n0 + wc + j * 16 + l16;
        const float bv = bias[n];
#pragma unroll
        for (int i = 0; i < 4; i++) {
            const int rbase = wr + i * 16 + quad * 4;
#pragma unroll
            for (int r = 0; r < 4; r++) {
                const int p = m_start + rbase + r;
                if (EXPERT && p >= cnt) continue;
                float v = acc[i][j][r] + bv;
                if (GELU) v = geluf(v);
                size_t drow;
                if (EXPERT) {
                    const int pp = off + p;
                    drow = SCATTER_C ? (size_t)row_ids[pp] : (size_t)pp;
                } else {
                    drow = (size_t)p;
                }
                Cmat[drow * (size_t)N + n] = (CT)v;
            }
        }
    }
}

extern "C" void kernel_launch(void* const* d_in, const int* in_sizes, int n_in,
                              void* d_out, int out_size, void* d_ws,
                              size_t ws_size, hipStream_t stream) {
    // 0 noise (unused), 1 genre(i32), 2 z, 3 mu_table, 4 sigma_table,
    // 5 Ws1, 6 bs1, 7 Ws2, 8 bs2, 9 We1, 10 be1, 11 We2, 12 be2  (all fp32)
    const int* genre = (const int*)d_in[1];
    const float* z = (const float*)d_in[2];
    const float* mu_t = (const float*)d_in[3];
    const float* sg_t = (const float*)d_in[4];
    const float* Ws1 = (const float*)d_in[5];
    const float* bs1 = (const float*)d_in[6];
    const float* Ws2 = (const float*)d_in[7];
    const float* bs2 = (const float*)d_in[8];
    const float* We1 = (const float*)d_in[9];
    const float* be1 = (const float*)d_in[10];
    const float* We2 = (const float*)d_in[11];
    const float* be2 = (const float*)d_in[12];
    float* out = (float*)d_out;

    // Workspace layout (~20 MB):
    //   [ 0, 4MB) ng   bf16 (dead after GEMM1)
    //   [ 0, 8MB) hp   bf16 (aliases ng+s1; written in GEMM3 when both dead)
    //   [ 4,12MB) s1   bf16 (dead after GEMM2)
    //   [12,20MB) s2   bf16
    //   [20MB,+17KB) bucket ints
    char* w = (char*)d_ws;
    bf16* ng = (bf16*)w;
    bf16* hp = (bf16*)w;
    bf16* s1 = (bf16*)(w + ((size_t)4 << 20));
    bf16* s2 = (bf16*)(w + ((size_t)12 << 20));
    char* wi = w + ((size_t)20 << 20);
    int* counts = (int*)wi;
    int* offsets = (int*)(wi + 64);
    int* cursors = (int*)(wi + 128);
    int* row_ids = (int*)(wi + 256);

    hipMemsetAsync(counts, 0, 64, stream);
    prep_kernel<<<B_ROWS, 64, 0, stream>>>(genre, z, mu_t, sg_t, ng, counts);
    scan_kernel<<<1, 64, 0, stream>>>(counts, offsets, cursors);
    scatter_kernel<<<B_ROWS / 256, 256, 0, stream>>>(genre, cursors, row_ids);

    // shared MLP
    gemm_kernel<false, false, false, true, bf16>
        <<<dim3(DIM / 128, B_ROWS / 128), 256, 0, stream>>>(
            ng, Ws1, bs1, s1, B_ROWS, DIM, IN_DIM, nullptr, nullptr, nullptr);
    gemm_kernel<false, false, false, true, bf16>
        <<<dim3(DIM / 128, B_ROWS / 128), 256, 0, stream>>>(
            s1, Ws2, bs2, s2, B_ROWS, DIM, DIM, nullptr, nullptr, nullptr);
    // expert layer 1: gather rows by bucket, gelu, write permuted h
    gemm_kernel<true, true, false, true, bf16>
        <<<dim3(DIM / 128, B_ROWS / 128, NG), 256, 0, stream>>>(
            s2, We1, be1, hp, B_ROWS, DIM, DIM, row_ids, offsets, counts);
    // expert layer 2: contiguous permuted h, scatter rows to fp32 out
    gemm_kernel<true, false, true, false, float>
        <<<dim3(DIM / 128, B_ROWS / 128, NG), 256, 0, stream>>>(
            hp, We2, be2, out, B_ROWS, DIM, DIM, row_ids, offsets, counts);
}

// Round 4
// 364.921 us; speedup vs baseline: 1.0832x; 1.0832x over previous
//
#include <hip/hip_runtime.h>
#include <hip/hip_bf16.h>

typedef __bf16 bf16;
typedef __bf16 bf16x8 __attribute__((ext_vector_type(8)));
typedef float floatx4 __attribute__((ext_vector_type(4)));

#define B_ROWS 4096
#define IN_DIM 512
#define DIM 1024
#define NG 10

__device__ __forceinline__ float geluf(float x) {
    return 0.5f * x * (1.0f + erff(x * 0.70710678118654752f));
}

// ---------------------------------------------------------------------------
// prep: ng[row] = bf16( mu[g] + (|sigma[g]|+eps) * z[row] ); histogram counts
// ---------------------------------------------------------------------------
__global__ void prep_kernel(const int* __restrict__ genre,
                            const float* __restrict__ z,
                            const float* __restrict__ mu_t,
                            const float* __restrict__ sg_t,
                            bf16* __restrict__ ng,
                            int* __restrict__ counts) {
    const int row = blockIdx.x;
    const int g = genre[row];
    const int c0 = threadIdx.x * 8;
    const float* zp = z + (size_t)row * IN_DIM + c0;
    const float* mp = mu_t + (size_t)g * IN_DIM + c0;
    const float* sp = sg_t + (size_t)g * IN_DIM + c0;
    floatx4 z0 = *(const floatx4*)zp, z1 = *(const floatx4*)(zp + 4);
    floatx4 m0 = *(const floatx4*)mp, m1 = *(const floatx4*)(mp + 4);
    floatx4 s0 = *(const floatx4*)sp, s1 = *(const floatx4*)(sp + 4);
    bf16x8 o;
#pragma unroll
    for (int i = 0; i < 4; i++) {
        o[i] = (bf16)(m0[i] + (fabsf(s0[i]) + 1e-8f) * z0[i]);
        o[i + 4] = (bf16)(m1[i] + (fabsf(s1[i]) + 1e-8f) * z1[i]);
    }
    *(bf16x8*)(ng + (size_t)row * IN_DIM + c0) = o;
    if (threadIdx.x == 0) atomicAdd(&counts[g], 1);
}

__global__ void scan_kernel(const int* __restrict__ counts,
                            int* __restrict__ offsets,
                            int* __restrict__ cursors) {
    if (threadIdx.x == 0 && blockIdx.x == 0) {
        int acc = 0;
        for (int g = 0; g < NG; g++) {
            offsets[g] = acc;
            cursors[g] = acc;
            acc += counts[g];
        }
        offsets[NG] = acc;
    }
}

__global__ void scatter_kernel(const int* __restrict__ genre,
                               int* __restrict__ cursors,
                               int* __restrict__ row_ids) {
    int row = blockIdx.x * blockDim.x + threadIdx.x;
    if (row < B_ROWS) {
        int g = genre[row];
        int pos = atomicAdd(&cursors[g], 1);
        row_ids[pos] = row;
    }
}

// ---------------------------------------------------------------------------
// GEMM: C = act(A @ B + bias).  A [M][K] bf16, B [K][N] fp32 (cvt at staging).
// 64x64 tile, BK=64: 1024+ blocks -> 4+ blocks/CU (round-3 fix: occupancy
// was 10% with 128x128 tiles / 256 blocks; latency-bound at 5 waves/CU).
// Each wave owns a 32x32 quadrant (2x2 16x16x32 frags, 16 acc VGPRs).
// B transposed on-the-fly into Bs[n][k] with k-block XOR swizzle.
// EXPERT: grid.z = genre; rows are bucket positions [0,count) at offsets[g].
// ---------------------------------------------------------------------------
template <bool EXPERT, bool GATHER_A, bool SCATTER_C, bool GELU, typename CT>
__global__ __launch_bounds__(256, 4) void gemm_kernel(
    const bf16* __restrict__ A, const float* __restrict__ Bmat,
    const float* __restrict__ bias, CT* __restrict__ Cmat,
    int M, int N, int K,
    const int* __restrict__ row_ids, const int* __restrict__ offsets,
    const int* __restrict__ counts) {
    int off = 0, cnt = M;
    if (EXPERT) {
        const int g = blockIdx.z;
        cnt = counts[g];
        if ((int)blockIdx.y * 64 >= cnt) return;
        off = offsets[g];
        Bmat += (size_t)g * K * N;
        bias += (size_t)g * N;
    }
    const int m_start = blockIdx.y * 64;
    const int n0 = blockIdx.x * 64;

    constexpr int BK = 64;
    constexpr int LK = BK + 8;  // 2-way bank alias only (free per m136)
    __shared__ bf16 As[64 * LK];
    __shared__ bf16 Bs[64 * LK];

    const int tid = threadIdx.x;
    const int lane = tid & 63;
    const int wave = tid >> 6;
    const int wrow = (wave >> 1) * 32;
    const int wcol = (wave & 1) * 32;
    const int quad = lane >> 4;
    const int l16 = lane & 15;

    // A staging: flat octet f = tid + i*256 (f<512) -> row f>>3, col (f&7)*8
    int a_r[2], a_c[2];
    size_t a_src[2];
#pragma unroll
    for (int i = 0; i < 2; i++) {
        int f = tid + i * 256;
        int r = f >> 3;
        int c = (f & 7) * 8;
        a_r[i] = r;
        a_c[i] = c;
        int p = m_start + r;
        size_t srow;
        if (EXPERT) {
            int pp = off + min(p, cnt - 1);
            srow = GATHER_A ? (size_t)row_ids[pp] : (size_t)pp;
        } else {
            srow = (size_t)p;
        }
        a_src[i] = srow * (size_t)K + c;
    }
    // B staging: f = tid + i*256 -> k_local f>>3, n-octet f&7
    int b_k[2], b_m[2];
#pragma unroll
    for (int i = 0; i < 2; i++) {
        int f = tid + i * 256;
        b_k[i] = f >> 3;
        b_m[i] = f & 7;
    }

    floatx4 acc[2][2];
#pragma unroll
    for (int i = 0; i < 2; i++)
#pragma unroll
        for (int j = 0; j < 2; j++)
#pragma unroll
            for (int r = 0; r < 4; r++) acc[i][j][r] = 0.0f;

    const int nK = K / BK;
    for (int kt = 0; kt < nK; kt++) {
        const int kbase = kt * BK;
#pragma unroll
        for (int i = 0; i < 2; i++) {
            bf16x8 va = *(const bf16x8*)(A + a_src[i] + kbase);
            *(bf16x8*)(As + a_r[i] * LK + a_c[i]) = va;
            // B: 8 n-contiguous fp32, cvt, scatter into Bs[n][k] swizzled
            const int kl = b_k[i];
            const int m = b_m[i];
            const float* brow = Bmat + (size_t)(kbase + kl) * N + n0 + m * 8;
            floatx4 v0 = *(const floatx4*)brow;
            floatx4 v1 = *(const floatx4*)(brow + 4);
            const int swk = (((kl >> 3) ^ m) << 3) + (kl & 7);
            bf16* bs = Bs + m * 8 * LK + swk;
#pragma unroll
            for (int j = 0; j < 4; j++) {
                bs[j * LK] = (bf16)v0[j];
                bs[(j + 4) * LK] = (bf16)v1[j];
            }
        }
        __syncthreads();
#pragma unroll
        for (int ks = 0; ks < BK / 32; ks++) {
            bf16x8 af[2], bfr[2];
#pragma unroll
            for (int i = 0; i < 2; i++)
                af[i] = *(const bf16x8*)(As + (wrow + i * 16 + l16) * LK +
                                         ks * 32 + quad * 8);
#pragma unroll
            for (int j = 0; j < 2; j++) {
                const int n = wcol + j * 16 + l16;
                const int kb = ks * 4 + quad;
                bfr[j] = *(const bf16x8*)(Bs + n * LK +
                                          ((kb ^ ((n >> 3) & 7)) << 3));
            }
#pragma unroll
            for (int i = 0; i < 2; i++)
#pragma unroll
                for (int j = 0; j < 2; j++)
                    acc[i][j] = __builtin_amdgcn_mfma_f32_16x16x32_bf16(
                        af[i], bfr[j], acc[i][j], 0, 0, 0);
        }
        __syncthreads();
    }

    // epilogue: C/D layout col = lane&15, row = quad*4 + reg  [m89-verified]
#pragma unroll
    for (int j = 0; j < 2; j++) {
        const int n = n0 + wcol + j * 16 + l16;
        const float bv = bias[n];
#pragma unroll
        for (int i = 0; i < 2; i++) {
            const int rbase = wrow + i * 16 + quad * 4;
#pragma unroll
            for (int r = 0; r < 4; r++) {
                const int p = m_start + rbase + r;
                if (EXPERT && p >= cnt) continue;
                float v = acc[i][j][r] + bv;
                if (GELU) v = geluf(v);
                size_t drow;
                if (EXPERT) {
                    const int pp = off + p;
                    drow = SCATTER_C ? (size_t)row_ids[pp] : (size_t)pp;
                } else {
                    drow = (size_t)p;
                }
                Cmat[drow * (size_t)N + n] = (CT)v;
            }
        }
    }
}

extern "C" void kernel_launch(void* const* d_in, const int* in_sizes, int n_in,
                              void* d_out, int out_size, void* d_ws,
                              size_t ws_size, hipStream_t stream) {
    // 0 noise (unused), 1 genre(i32), 2 z, 3 mu_table, 4 sigma_table,
    // 5 Ws1, 6 bs1, 7 Ws2, 8 bs2, 9 We1, 10 be1, 11 We2, 12 be2  (all fp32)
    const int* genre = (const int*)d_in[1];
    const float* z = (const float*)d_in[2];
    const float* mu_t = (const float*)d_in[3];
    const float* sg_t = (const float*)d_in[4];
    const float* Ws1 = (const float*)d_in[5];
    const float* bs1 = (const float*)d_in[6];
    const float* Ws2 = (const float*)d_in[7];
    const float* bs2 = (const float*)d_in[8];
    const float* We1 = (const float*)d_in[9];
    const float* be1 = (const float*)d_in[10];
    const float* We2 = (const float*)d_in[11];
    const float* be2 = (const float*)d_in[12];
    float* out = (float*)d_out;

    // Workspace layout (~20 MB):
    //   [ 0, 4MB) ng   bf16 (dead after GEMM1)
    //   [ 0, 8MB) hp   bf16 (aliases ng+s1; written in GEMM3 when both dead)
    //   [ 4,12MB) s1   bf16 (dead after GEMM2)
    //   [12,20MB) s2   bf16
    //   [20MB,+17KB) bucket ints
    char* w = (char*)d_ws;
    bf16* ng = (bf16*)w;
    bf16* hp = (bf16*)w;
    bf16* s1 = (bf16*)(w + ((size_t)4 << 20));
    bf16* s2 = (bf16*)(w + ((size_t)12 << 20));
    char* wi = w + ((size_t)20 << 20);
    int* counts = (int*)wi;
    int* offsets = (int*)(wi + 64);
    int* cursors = (int*)(wi + 128);
    int* row_ids = (int*)(wi + 256);

    hipMemsetAsync(counts, 0, 64, stream);
    prep_kernel<<<B_ROWS, 64, 0, stream>>>(genre, z, mu_t, sg_t, ng, counts);
    scan_kernel<<<1, 64, 0, stream>>>(counts, offsets, cursors);
    scatter_kernel<<<B_ROWS / 256, 256, 0, stream>>>(genre, cursors, row_ids);

    // shared MLP
    gemm_kernel<false, false, false, true, bf16>
        <<<dim3(DIM / 64, B_ROWS / 64), 256, 0, stream>>>(
            ng, Ws1, bs1, s1, B_ROWS, DIM, IN_DIM, nullptr, nullptr, nullptr);
    gemm_kernel<false, false, false, true, bf16>
        <<<dim3(DIM / 64, B_ROWS / 64), 256, 0, stream>>>(
            s1, Ws2, bs2, s2, B_ROWS, DIM, DIM, nullptr, nullptr, nullptr);
    // expert layer 1: gather rows by bucket, gelu, write permuted h
    gemm_kernel<true, true, false, true, bf16>
        <<<dim3(DIM / 64, B_ROWS / 64, NG), 256, 0, stream>>>(
            s2, We1, be1, hp, B_ROWS, DIM, DIM, row_ids, offsets, counts);
    // expert layer 2: contiguous permuted h, scatter rows to fp32 out
    gemm_kernel<true, false, true, false, float>
        <<<dim3(DIM / 64, B_ROWS / 64, NG), 256, 0, stream>>>(
            hp, We2, be2, out, B_ROWS, DIM, DIM, row_ids, offsets, counts);
}

// Round 5
// 327.556 us; speedup vs baseline: 1.2068x; 1.1141x over previous
//
#include <hip/hip_runtime.h>
#include <hip/hip_bf16.h>

typedef __bf16 bf16;
typedef __bf16 bf16x8 __attribute__((ext_vector_type(8)));
typedef float floatx4 __attribute__((ext_vector_type(4)));

#define B_ROWS 4096
#define IN_DIM 512
#define DIM 1024
#define NG 10

__device__ __forceinline__ float geluf(float x) {
    return 0.5f * x * (1.0f + erff(x * 0.70710678118654752f));
}

// async global->LDS, 16B per lane; LDS dest = wave-uniform base + lane*16
__device__ __forceinline__ void async16(void* lds, const void* g) {
    __builtin_amdgcn_global_load_lds(
        (const __attribute__((address_space(1))) unsigned int*)g,
        (__attribute__((address_space(3))) unsigned int*)lds, 16, 0, 0);
}

// ---------------------------------------------------------------------------
// prep: ng[row] = bf16( mu[g] + (|sigma[g]|+eps) * z[row] ); histogram counts
// ---------------------------------------------------------------------------
__global__ void prep_kernel(const int* __restrict__ genre,
                            const float* __restrict__ z,
                            const float* __restrict__ mu_t,
                            const float* __restrict__ sg_t,
                            bf16* __restrict__ ng,
                            int* __restrict__ counts) {
    const int row = blockIdx.x;
    const int g = genre[row];
    const int c0 = threadIdx.x * 8;
    const float* zp = z + (size_t)row * IN_DIM + c0;
    const float* mp = mu_t + (size_t)g * IN_DIM + c0;
    const float* sp = sg_t + (size_t)g * IN_DIM + c0;
    floatx4 z0 = *(const floatx4*)zp, z1 = *(const floatx4*)(zp + 4);
    floatx4 m0 = *(const floatx4*)mp, m1 = *(const floatx4*)(mp + 4);
    floatx4 s0 = *(const floatx4*)sp, s1 = *(const floatx4*)(sp + 4);
    bf16x8 o;
#pragma unroll
    for (int i = 0; i < 4; i++) {
        o[i] = (bf16)(m0[i] + (fabsf(s0[i]) + 1e-8f) * z0[i]);
        o[i + 4] = (bf16)(m1[i] + (fabsf(s1[i]) + 1e-8f) * z1[i]);
    }
    *(bf16x8*)(ng + (size_t)row * IN_DIM + c0) = o;
    if (threadIdx.x == 0) atomicAdd(&counts[g], 1);
}

__global__ void scan_kernel(const int* __restrict__ counts,
                            int* __restrict__ offsets,
                            int* __restrict__ cursors) {
    if (threadIdx.x == 0 && blockIdx.x == 0) {
        int acc = 0;
        for (int g = 0; g < NG; g++) {
            offsets[g] = acc;
            cursors[g] = acc;
            acc += counts[g];
        }
        offsets[NG] = acc;
    }
}

__global__ void scatter_kernel(const int* __restrict__ genre,
                               int* __restrict__ cursors,
                               int* __restrict__ row_ids) {
    int row = blockIdx.x * blockDim.x + threadIdx.x;
    if (row < B_ROWS) {
        int g = genre[row];
        int pos = atomicAdd(&cursors[g], 1);
        row_ids[pos] = row;
    }
}

// ---------------------------------------------------------------------------
// fused transpose + fp32->bf16 downconvert of ALL weights, one launch.
// in [R][C] fp32 -> out [C][R] bf16. 32x32 tiles, block (32,8).
// flat tile id: [0,512) Ws1; [512,1536) Ws2; [1536,11776) We1; rest We2.
// ---------------------------------------------------------------------------
__global__ void transpose_all_kernel(const float* __restrict__ Ws1,
                                     const float* __restrict__ Ws2,
                                     const float* __restrict__ We1,
                                     const float* __restrict__ We2,
                                     bf16* __restrict__ WT1,
                                     bf16* __restrict__ WT2,
                                     bf16* __restrict__ WE1T,
                                     bf16* __restrict__ WE2T) {
    int b = blockIdx.x;
    const float* src;
    bf16* dst;
    int R;
    if (b < 512) {  // Ws1: 512x1024, 32 x-tiles
        src = Ws1; dst = WT1; R = 512;
    } else if (b < 1536) {
        b -= 512; src = Ws2; dst = WT2; R = 1024;
    } else if (b < 11776) {
        b -= 1536;
        int e = b >> 10; b &= 1023;
        src = We1 + (size_t)e * DIM * DIM;
        dst = WE1T + (size_t)e * DIM * DIM;
        R = 1024;
    } else {
        b -= 11776;
        int e = b >> 10; b &= 1023;
        src = We2 + (size_t)e * DIM * DIM;
        dst = WE2T + (size_t)e * DIM * DIM;
        R = 1024;
    }
    const int c0 = (b & 31) * 32;      // C==1024 always: 32 x-tiles
    const int r0 = (b >> 5) * 32;
    __shared__ float t[32][33];
#pragma unroll
    for (int i = threadIdx.y; i < 32; i += 8)
        t[i][threadIdx.x] = src[(size_t)(r0 + i) * 1024 + c0 + threadIdx.x];
    __syncthreads();
#pragma unroll
    for (int i = threadIdx.y; i < 32; i += 8)
        dst[(size_t)(c0 + i) * R + r0 + threadIdx.x] = (bf16)t[threadIdx.x][i];
}

// ---------------------------------------------------------------------------
// GEMM: C = act(A @ BT^T + bias). A [M][K] bf16, BT [N][K] bf16.
// 64x64 tile, BK=64, m97-style async staging: global_load_lds width=16 for
// both operands. LDS slot s (=wave*64+lane [+256]) holds global octet
// (row=s>>3, colblk=(s&7)^(row&7)) — source-side XOR swizzle so fragment
// ds_read_b128 spreads 8 lanes/bank-group (inherent minimum, no conflicts).
// EXPERT: grid.z = genre; rows are bucket positions [0,count) at offsets[g].
// ---------------------------------------------------------------------------
template <bool EXPERT, bool GATHER_A, bool SCATTER_C, bool GELU, typename CT>
__global__ __launch_bounds__(256, 4) void gemm_kernel(
    const bf16* __restrict__ A, const bf16* __restrict__ BT,
    const float* __restrict__ bias, CT* __restrict__ Cmat,
    int M, int N, int K,
    const int* __restrict__ row_ids, const int* __restrict__ offsets,
    const int* __restrict__ counts) {
    int off = 0, cnt = M;
    if (EXPERT) {
        const int g = blockIdx.z;
        cnt = counts[g];
        if ((int)blockIdx.y * 64 >= cnt) return;
        off = offsets[g];
        BT += (size_t)g * N * K;
        bias += (size_t)g * N;
    }
    const int m_start = blockIdx.y * 64;
    const int n0 = blockIdx.x * 64;

    __shared__ bf16 As[64 * 64];
    __shared__ bf16 Bs[64 * 64];

    const int tid = threadIdx.x;
    const int lane = tid & 63;
    const int wave = tid >> 6;
    const int wrow = (wave >> 1) * 32;
    const int wcol = (wave & 1) * 32;
    const int quad = lane >> 4;
    const int l16 = lane & 15;

    // staging: issue i covers slots [i*256, i*256+256); this thread's slot:
    const bf16* a_src[2];
    const bf16* b_src[2];
    bf16* a_dst[2];
    bf16* b_dst[2];
#pragma unroll
    for (int i = 0; i < 2; i++) {
        const int s = i * 256 + tid;
        const int row = s >> 3;
        const int col = ((s & 7) ^ (row & 7)) * 8;
        // wave-uniform LDS base; HW adds lane*16
        const int sbase = i * 256 + wave * 64;
        a_dst[i] = As + sbase * 8;
        b_dst[i] = Bs + sbase * 8;
        int p = m_start + row;
        size_t arow;
        if (EXPERT) {
            int pp = off + min(p, cnt - 1);
            arow = GATHER_A ? (size_t)row_ids[pp] : (size_t)pp;
        } else {
            arow = (size_t)p;
        }
        a_src[i] = A + arow * (size_t)K + col;
        b_src[i] = BT + (size_t)(n0 + row) * K + col;
    }

    floatx4 acc[2][2];
#pragma unroll
    for (int i = 0; i < 2; i++)
#pragma unroll
        for (int j = 0; j < 2; j++)
#pragma unroll
            for (int r = 0; r < 4; r++) acc[i][j][r] = 0.0f;

    const int nK = K / 64;
    for (int kt = 0; kt < nK; kt++) {
        const int kbase = kt * 64;
        async16(a_dst[0], a_src[0] + kbase);
        async16(a_dst[1], a_src[1] + kbase);
        async16(b_dst[0], b_src[0] + kbase);
        async16(b_dst[1], b_src[1] + kbase);
        __syncthreads();
#pragma unroll
        for (int ks = 0; ks < 2; ks++) {
            bf16x8 af[2], bfr[2];
#pragma unroll
            for (int i = 0; i < 2; i++) {
                const int r = wrow + i * 16 + l16;
                const int cb = ks * 4 + quad;
                af[i] = *(const bf16x8*)(As + (r * 8 + (cb ^ (r & 7))) * 8);
            }
#pragma unroll
            for (int j = 0; j < 2; j++) {
                const int n = wcol + j * 16 + l16;
                const int cb = ks * 4 + quad;
                bfr[j] = *(const bf16x8*)(Bs + (n * 8 + (cb ^ (n & 7))) * 8);
            }
#pragma unroll
            for (int i = 0; i < 2; i++)
#pragma unroll
                for (int j = 0; j < 2; j++)
                    acc[i][j] = __builtin_amdgcn_mfma_f32_16x16x32_bf16(
                        af[i], bfr[j], acc[i][j], 0, 0, 0);
        }
        __syncthreads();
    }

    // epilogue: C/D layout col = lane&15, row = quad*4 + reg  [m89-verified]
#pragma unroll
    for (int j = 0; j < 2; j++) {
        const int n = n0 + wcol + j * 16 + l16;
        const float bv = bias[n];
#pragma unroll
        for (int i = 0; i < 2; i++) {
            const int rbase = wrow + i * 16 + quad * 4;
#pragma unroll
            for (int r = 0; r < 4; r++) {
                const int p = m_start + rbase + r;
                if (EXPERT && p >= cnt) continue;
                float v = acc[i][j][r] + bv;
                if (GELU) v = geluf(v);
                size_t drow;
                if (EXPERT) {
                    const int pp = off + p;
                    drow = SCATTER_C ? (size_t)row_ids[pp] : (size_t)pp;
                } else {
                    drow = (size_t)p;
                }
                Cmat[drow * (size_t)N + n] = (CT)v;
            }
        }
    }
}

extern "C" void kernel_launch(void* const* d_in, const int* in_sizes, int n_in,
                              void* d_out, int out_size, void* d_ws,
                              size_t ws_size, hipStream_t stream) {
    // 0 noise (unused), 1 genre(i32), 2 z, 3 mu_table, 4 sigma_table,
    // 5 Ws1, 6 bs1, 7 Ws2, 8 bs2, 9 We1, 10 be1, 11 We2, 12 be2  (all fp32)
    const int* genre = (const int*)d_in[1];
    const float* z = (const float*)d_in[2];
    const float* mu_t = (const float*)d_in[3];
    const float* sg_t = (const float*)d_in[4];
    const float* Ws1 = (const float*)d_in[5];
    const float* bs1 = (const float*)d_in[6];
    const float* Ws2 = (const float*)d_in[7];
    const float* bs2 = (const float*)d_in[8];
    const float* We1 = (const float*)d_in[9];
    const float* be1 = (const float*)d_in[10];
    const float* We2 = (const float*)d_in[11];
    const float* be2 = (const float*)d_in[12];
    float* out = (float*)d_out;

    // Workspace (~63.1 MB): ints first, weights last.
    //   [0, 64KB)          counts/offsets/cursors/row_ids
    //   [64KB, +4MB)       ng bf16   (dead after GEMM1)
    //   [64KB, +8MB)       hp bf16   (aliases ng+s1; written in GEMM3)
    //   [64KB+4MB, +8MB)   s1 bf16   (dead after GEMM2)
    //   [64KB+12MB, +8MB)  s2 bf16
    //   [64KB+20MB, +1MB)  WT1 bf16 [1024][512]
    //   then WT2 [1024][1024], WE1T [10][1024][1024], WE2T [10][1024][1024]
    char* w = (char*)d_ws;
    int* counts = (int*)w;
    int* offsets = (int*)(w + 256);
    int* cursors = (int*)(w + 512);
    int* row_ids = (int*)(w + 1024);
    char* wb = w + (64 << 10);
    bf16* ng = (bf16*)wb;
    bf16* hp = (bf16*)wb;
    bf16* s1 = (bf16*)(wb + ((size_t)4 << 20));
    bf16* s2 = (bf16*)(wb + ((size_t)12 << 20));
    bf16* WT1 = (bf16*)(wb + ((size_t)20 << 20));
    bf16* WT2 = WT1 + (size_t)IN_DIM * DIM;
    bf16* WE1T = WT2 + (size_t)DIM * DIM;
    bf16* WE2T = WE1T + (size_t)NG * DIM * DIM;

    hipMemsetAsync(counts, 0, 64, stream);
    prep_kernel<<<B_ROWS, 64, 0, stream>>>(genre, z, mu_t, sg_t, ng, counts);
    scan_kernel<<<1, 64, 0, stream>>>(counts, offsets, cursors);
    scatter_kernel<<<B_ROWS / 256, 256, 0, stream>>>(genre, cursors, row_ids);
    transpose_all_kernel<<<22016, dim3(32, 8), 0, stream>>>(
        Ws1, Ws2, We1, We2, WT1, WT2, WE1T, WE2T);

    // shared MLP
    gemm_kernel<false, false, false, true, bf16>
        <<<dim3(DIM / 64, B_ROWS / 64), 256, 0, stream>>>(
            ng, WT1, bs1, s1, B_ROWS, DIM, IN_DIM, nullptr, nullptr, nullptr);
    gemm_kernel<false, false, false, true, bf16>
        <<<dim3(DIM / 64, B_ROWS / 64), 256, 0, stream>>>(
            s1, WT2, bs2, s2, B_ROWS, DIM, DIM, nullptr, nullptr, nullptr);
    // expert layer 1: gather rows by bucket, gelu, write permuted h
    gemm_kernel<true, true, false, true, bf16>
        <<<dim3(DIM / 64, B_ROWS / 64, NG), 256, 0, stream>>>(
            s2, WE1T, be1, hp, B_ROWS, DIM, DIM, row_ids, offsets, counts);
    // expert layer 2: contiguous permuted h, scatter rows to fp32 out
    gemm_kernel<true, false, true, false, float>
        <<<dim3(DIM / 64, B_ROWS / 64, NG), 256, 0, stream>>>(
            hp, WE2T, be2, out, B_ROWS, DIM, DIM, row_ids, offsets, counts);
}

// Round 6
// 262.386 us; speedup vs baseline: 1.5065x; 1.2484x over previous
//
#include <hip/hip_runtime.h>
#include <hip/hip_bf16.h>

typedef __bf16 bf16;
typedef __bf16 bf16x8 __attribute__((ext_vector_type(8)));
typedef float floatx4 __attribute__((ext_vector_type(4)));

#define B_ROWS 4096
#define IN_DIM 512
#define DIM 1024
#define NG 10

__device__ __forceinline__ float geluf(float x) {
    return 0.5f * x * (1.0f + erff(x * 0.70710678118654752f));
}

// async global->LDS, 16B per lane; LDS dest = wave-uniform base + lane*16
__device__ __forceinline__ void async16(void* lds, const void* g) {
    __builtin_amdgcn_global_load_lds(
        (const __attribute__((address_space(1))) unsigned int*)g,
        (__attribute__((address_space(3))) unsigned int*)lds, 16, 0, 0);
}

// ---------------------------------------------------------------------------
// prep: ng = bf16( mu[g] + (|sigma[g]|+eps) * z ). Pure elementwise, no
// atomics (round-5 fix: per-block device atomics + 64-thread blocks made the
// old prep 50.9 us at 0.3% VALUBusy). 1024 blocks x 256 thr, 1 octet/thread.
// ---------------------------------------------------------------------------
__global__ void prep_kernel(const int* __restrict__ genre,
                            const float* __restrict__ z,
                            const float* __restrict__ mu_t,
                            const float* __restrict__ sg_t,
                            bf16* __restrict__ ng) {
    const int t = blockIdx.x * 256 + threadIdx.x;
    const int row = t >> 6;            // IN_DIM/8 = 64 octets per row
    const int c0 = (t & 63) * 8;
    const int g = genre[row];
    const float* zp = z + (size_t)row * IN_DIM + c0;
    const float* mp = mu_t + (size_t)g * IN_DIM + c0;
    const float* sp = sg_t + (size_t)g * IN_DIM + c0;
    floatx4 z0 = *(const floatx4*)zp, z1 = *(const floatx4*)(zp + 4);
    floatx4 m0 = *(const floatx4*)mp, m1 = *(const floatx4*)(mp + 4);
    floatx4 s0 = *(const floatx4*)sp, s1 = *(const floatx4*)(sp + 4);
    bf16x8 o;
#pragma unroll
    for (int i = 0; i < 4; i++) {
        o[i] = (bf16)(m0[i] + (fabsf(s0[i]) + 1e-8f) * z0[i]);
        o[i + 4] = (bf16)(m1[i] + (fabsf(s1[i]) + 1e-8f) * z1[i]);
    }
    *(bf16x8*)(ng + (size_t)row * IN_DIM + c0) = o;
}

// ---------------------------------------------------------------------------
// bucket: histogram + prefix + scatter in ONE block (1024 thr, 4 rows each),
// all via LDS atomics — replaces count/scan/scatter with zero device atomics.
// ---------------------------------------------------------------------------
__global__ void bucket_kernel(const int* __restrict__ genre,
                              int* __restrict__ counts,
                              int* __restrict__ offsets,
                              int* __restrict__ row_ids) {
    __shared__ int hist[NG];
    __shared__ int base[NG];
    const int tid = threadIdx.x;
    if (tid < NG) hist[tid] = 0;
    __syncthreads();
    int g[4];
#pragma unroll
    for (int i = 0; i < 4; i++) {
        g[i] = genre[tid + i * 1024];
        atomicAdd(&hist[g[i]], 1);
    }
    __syncthreads();
    if (tid == 0) {
        int acc = 0;
        for (int e = 0; e < NG; e++) {
            base[e] = acc;
            counts[e] = hist[e];
            offsets[e] = acc;
            acc += hist[e];
        }
        offsets[NG] = acc;
    }
    __syncthreads();
    if (tid < NG) hist[tid] = base[tid];  // reuse as cursors
    __syncthreads();
#pragma unroll
    for (int i = 0; i < 4; i++) {
        int pos = atomicAdd(&hist[g[i]], 1);
        row_ids[pos] = tid + i * 1024;
    }
}

// ---------------------------------------------------------------------------
// fused transpose + fp32->bf16 downconvert of ALL weights, one launch.
// in [R][C] fp32 -> out [C][R] bf16. 32x32 tiles, block (32,8).
// ---------------------------------------------------------------------------
__global__ void transpose_all_kernel(const float* __restrict__ Ws1,
                                     const float* __restrict__ Ws2,
                                     const float* __restrict__ We1,
                                     const float* __restrict__ We2,
                                     bf16* __restrict__ WT1,
                                     bf16* __restrict__ WT2,
                                     bf16* __restrict__ WE1T,
                                     bf16* __restrict__ WE2T) {
    int b = blockIdx.x;
    const float* src;
    bf16* dst;
    int R;
    if (b < 512) {
        src = Ws1; dst = WT1; R = 512;
    } else if (b < 1536) {
        b -= 512; src = Ws2; dst = WT2; R = 1024;
    } else if (b < 11776) {
        b -= 1536;
        int e = b >> 10; b &= 1023;
        src = We1 + (size_t)e * DIM * DIM;
        dst = WE1T + (size_t)e * DIM * DIM;
        R = 1024;
    } else {
        b -= 11776;
        int e = b >> 10; b &= 1023;
        src = We2 + (size_t)e * DIM * DIM;
        dst = WE2T + (size_t)e * DIM * DIM;
        R = 1024;
    }
    const int c0 = (b & 31) * 32;
    const int r0 = (b >> 5) * 32;
    __shared__ float t[32][33];
#pragma unroll
    for (int i = threadIdx.y; i < 32; i += 8)
        t[i][threadIdx.x] = src[(size_t)(r0 + i) * 1024 + c0 + threadIdx.x];
    __syncthreads();
#pragma unroll
    for (int i = threadIdx.y; i < 32; i += 8)
        dst[(size_t)(c0 + i) * R + r0 + threadIdx.x] = (bf16)t[threadIdx.x][i];
}

// ---------------------------------------------------------------------------
// GEMM: C = act(A @ BT^T + bias). A [M][K] bf16, BT [N][K] bf16.
// 64x64 tile, BK=128 (round-6: halves the vmcnt(0)-drain barrier count vs
// BK=64; we are barrier-latency-bound at MfmaUtil~5%). LDS 2x16KB -> still
// 4 blocks/CU. m97-style global_load_lds width=16 staging, source-side XOR
// swizzle over 16 octets/row: slot s -> (row=s>>4, colblk=(s&15)^(row&15)).
// EXPERT: grid.z = genre; rows are bucket positions [0,count) at offsets[g].
// ---------------------------------------------------------------------------
template <bool EXPERT, bool GATHER_A, bool SCATTER_C, bool GELU, typename CT>
__global__ __launch_bounds__(256, 4) void gemm_kernel(
    const bf16* __restrict__ A, const bf16* __restrict__ BT,
    const float* __restrict__ bias, CT* __restrict__ Cmat,
    int M, int N, int K,
    const int* __restrict__ row_ids, const int* __restrict__ offsets,
    const int* __restrict__ counts) {
    int off = 0, cnt = M;
    if (EXPERT) {
        const int g = blockIdx.z;
        cnt = counts[g];
        if ((int)blockIdx.y * 64 >= cnt) return;
        off = offsets[g];
        BT += (size_t)g * N * K;
        bias += (size_t)g * N;
    }
    const int m_start = blockIdx.y * 64;
    const int n0 = blockIdx.x * 64;

    constexpr int BK = 128;  // 16 octets per row
    __shared__ bf16 As[64 * BK];
    __shared__ bf16 Bs[64 * BK];

    const int tid = threadIdx.x;
    const int lane = tid & 63;
    const int wave = tid >> 6;
    const int wrow = (wave >> 1) * 32;
    const int wcol = (wave & 1) * 32;
    const int quad = lane >> 4;
    const int l16 = lane & 15;

    // staging: 1024 slots (64 rows x 16 octets); issue i covers [i*256,+256)
    const bf16* a_src[4];
    const bf16* b_src[4];
    bf16* a_dst[4];
    bf16* b_dst[4];
#pragma unroll
    for (int i = 0; i < 4; i++) {
        const int s = i * 256 + tid;
        const int row = s >> 4;
        const int col = ((s & 15) ^ (row & 15)) * 8;
        const int sbase = i * 256 + wave * 64;  // wave-uniform; HW adds lane*16
        a_dst[i] = As + sbase * 8;
        b_dst[i] = Bs + sbase * 8;
        int p = m_start + row;
        size_t arow;
        if (EXPERT) {
            int pp = off + min(p, cnt - 1);
            arow = GATHER_A ? (size_t)row_ids[pp] : (size_t)pp;
        } else {
            arow = (size_t)p;
        }
        a_src[i] = A + arow * (size_t)K + col;
        b_src[i] = BT + (size_t)(n0 + row) * K + col;
    }

    floatx4 acc[2][2];
#pragma unroll
    for (int i = 0; i < 2; i++)
#pragma unroll
        for (int j = 0; j < 2; j++)
#pragma unroll
            for (int r = 0; r < 4; r++) acc[i][j][r] = 0.0f;

    const int nK = K / BK;
    for (int kt = 0; kt < nK; kt++) {
        const int kbase = kt * BK;
#pragma unroll
        for (int i = 0; i < 4; i++) async16(a_dst[i], a_src[i] + kbase);
#pragma unroll
        for (int i = 0; i < 4; i++) async16(b_dst[i], b_src[i] + kbase);
        __syncthreads();
#pragma unroll
        for (int ks = 0; ks < 4; ks++) {
            bf16x8 af[2], bfr[2];
            const int cb = ks * 4 + quad;
#pragma unroll
            for (int i = 0; i < 2; i++) {
                const int r = wrow + i * 16 + l16;
                af[i] = *(const bf16x8*)(As + (r * 16 + (cb ^ (r & 15))) * 8);
            }
#pragma unroll
            for (int j = 0; j < 2; j++) {
                const int n = wcol + j * 16 + l16;
                bfr[j] = *(const bf16x8*)(Bs + (n * 16 + (cb ^ (n & 15))) * 8);
            }
#pragma unroll
            for (int i = 0; i < 2; i++)
#pragma unroll
                for (int j = 0; j < 2; j++)
                    acc[i][j] = __builtin_amdgcn_mfma_f32_16x16x32_bf16(
                        af[i], bfr[j], acc[i][j], 0, 0, 0);
        }
        __syncthreads();
    }

    // epilogue: C/D layout col = lane&15, row = quad*4 + reg  [m89-verified]
#pragma unroll
    for (int j = 0; j < 2; j++) {
        const int n = n0 + wcol + j * 16 + l16;
        const float bv = bias[n];
#pragma unroll
        for (int i = 0; i < 2; i++) {
            const int rbase = wrow + i * 16 + quad * 4;
#pragma unroll
            for (int r = 0; r < 4; r++) {
                const int p = m_start + rbase + r;
                if (EXPERT && p >= cnt) continue;
                float v = acc[i][j][r] + bv;
                if (GELU) v = geluf(v);
                size_t drow;
                if (EXPERT) {
                    const int pp = off + p;
                    drow = SCATTER_C ? (size_t)row_ids[pp] : (size_t)pp;
                } else {
                    drow = (size_t)p;
                }
                Cmat[drow * (size_t)N + n] = (CT)v;
            }
        }
    }
}

extern "C" void kernel_launch(void* const* d_in, const int* in_sizes, int n_in,
                              void* d_out, int out_size, void* d_ws,
                              size_t ws_size, hipStream_t stream) {
    // 0 noise (unused), 1 genre(i32), 2 z, 3 mu_table, 4 sigma_table,
    // 5 Ws1, 6 bs1, 7 Ws2, 8 bs2, 9 We1, 10 be1, 11 We2, 12 be2  (all fp32)
    const int* genre = (const int*)d_in[1];
    const float* z = (const float*)d_in[2];
    const float* mu_t = (const float*)d_in[3];
    const float* sg_t = (const float*)d_in[4];
    const float* Ws1 = (const float*)d_in[5];
    const float* bs1 = (const float*)d_in[6];
    const float* Ws2 = (const float*)d_in[7];
    const float* bs2 = (const float*)d_in[8];
    const float* We1 = (const float*)d_in[9];
    const float* be1 = (const float*)d_in[10];
    const float* We2 = (const float*)d_in[11];
    const float* be2 = (const float*)d_in[12];
    float* out = (float*)d_out;

    // Workspace (~63.1 MB): ints first, weights last.
    char* w = (char*)d_ws;
    int* counts = (int*)w;
    int* offsets = (int*)(w + 256);
    int* row_ids = (int*)(w + 1024);
    char* wb = w + (64 << 10);
    bf16* ng = (bf16*)wb;
    bf16* hp = (bf16*)wb;
    bf16* s1 = (bf16*)(wb + ((size_t)4 << 20));
    bf16* s2 = (bf16*)(wb + ((size_t)12 << 20));
    bf16* WT1 = (bf16*)(wb + ((size_t)20 << 20));
    bf16* WT2 = WT1 + (size_t)IN_DIM * DIM;
    bf16* WE1T = WT2 + (size_t)DIM * DIM;
    bf16* WE2T = WE1T + (size_t)NG * DIM * DIM;

    bucket_kernel<<<1, 1024, 0, stream>>>(genre, counts, offsets, row_ids);
    prep_kernel<<<B_ROWS * IN_DIM / 8 / 256, 256, 0, stream>>>(genre, z, mu_t,
                                                               sg_t, ng);
    transpose_all_kernel<<<22016, dim3(32, 8), 0, stream>>>(
        Ws1, Ws2, We1, We2, WT1, WT2, WE1T, WE2T);

    // shared MLP
    gemm_kernel<false, false, false, true, bf16>
        <<<dim3(DIM / 64, B_ROWS / 64), 256, 0, stream>>>(
            ng, WT1, bs1, s1, B_ROWS, DIM, IN_DIM, nullptr, nullptr, nullptr);
    gemm_kernel<false, false, false, true, bf16>
        <<<dim3(DIM / 64, B_ROWS / 64), 256, 0, stream>>>(
            s1, WT2, bs2, s2, B_ROWS, DIM, DIM, nullptr, nullptr, nullptr);
    // expert layer 1: gather rows by bucket, gelu, write permuted h
    gemm_kernel<true, true, false, true, bf16>
        <<<dim3(DIM / 64, B_ROWS / 64, NG), 256, 0, stream>>>(
            s2, WE1T, be1, hp, B_ROWS, DIM, DIM, row_ids, offsets, counts);
    // expert layer 2: contiguous permuted h, scatter rows to fp32 out
    gemm_kernel<true, false, true, false, float>
        <<<dim3(DIM / 64, B_ROWS / 64, NG), 256, 0, stream>>>(
            hp, WE2T, be2, out, B_ROWS, DIM, DIM, row_ids, offsets, counts);
}

// Round 7
// 254.115 us; speedup vs baseline: 1.5555x; 1.0326x over previous
//
#include <hip/hip_runtime.h>
#include <hip/hip_bf16.h>

typedef __bf16 bf16;
typedef __bf16 bf16x8 __attribute__((ext_vector_type(8)));
typedef float floatx4 __attribute__((ext_vector_type(4)));

#define B_ROWS 4096
#define IN_DIM 512
#define DIM 1024
#define NG 10

__device__ __forceinline__ float geluf(float x) {
    return 0.5f * x * (1.0f + erff(x * 0.70710678118654752f));
}

// async global->LDS, 16B per lane; LDS dest = wave-uniform base + lane*16
__device__ __forceinline__ void async16(void* lds, const void* g) {
    __builtin_amdgcn_global_load_lds(
        (const __attribute__((address_space(1))) unsigned int*)g,
        (__attribute__((address_space(3))) unsigned int*)lds, 16, 0, 0);
}

// ---------------------------------------------------------------------------
// prep: ng = bf16( mu[g] + (|sigma[g]|+eps) * z ). Pure elementwise.
// ---------------------------------------------------------------------------
__global__ void prep_kernel(const int* __restrict__ genre,
                            const float* __restrict__ z,
                            const float* __restrict__ mu_t,
                            const float* __restrict__ sg_t,
                            bf16* __restrict__ ng) {
    const int t = blockIdx.x * 256 + threadIdx.x;
    const int row = t >> 6;            // IN_DIM/8 = 64 octets per row
    const int c0 = (t & 63) * 8;
    const int g = genre[row];
    const float* zp = z + (size_t)row * IN_DIM + c0;
    const float* mp = mu_t + (size_t)g * IN_DIM + c0;
    const float* sp = sg_t + (size_t)g * IN_DIM + c0;
    floatx4 z0 = *(const floatx4*)zp, z1 = *(const floatx4*)(zp + 4);
    floatx4 m0 = *(const floatx4*)mp, m1 = *(const floatx4*)(mp + 4);
    floatx4 s0 = *(const floatx4*)sp, s1 = *(const floatx4*)(sp + 4);
    bf16x8 o;
#pragma unroll
    for (int i = 0; i < 4; i++) {
        o[i] = (bf16)(m0[i] + (fabsf(s0[i]) + 1e-8f) * z0[i]);
        o[i + 4] = (bf16)(m1[i] + (fabsf(s1[i]) + 1e-8f) * z1[i]);
    }
    *(bf16x8*)(ng + (size_t)row * IN_DIM + c0) = o;
}

// ---------------------------------------------------------------------------
// bucket: histogram + prefix + scatter in ONE block (1024 thr), LDS atomics.
// ---------------------------------------------------------------------------
__global__ void bucket_kernel(const int* __restrict__ genre,
                              int* __restrict__ counts,
                              int* __restrict__ offsets,
                              int* __restrict__ row_ids) {
    __shared__ int hist[NG];
    __shared__ int base[NG];
    const int tid = threadIdx.x;
    if (tid < NG) hist[tid] = 0;
    __syncthreads();
    int g[4];
#pragma unroll
    for (int i = 0; i < 4; i++) {
        g[i] = genre[tid + i * 1024];
        atomicAdd(&hist[g[i]], 1);
    }
    __syncthreads();
    if (tid == 0) {
        int acc = 0;
        for (int e = 0; e < NG; e++) {
            base[e] = acc;
            counts[e] = hist[e];
            offsets[e] = acc;
            acc += hist[e];
        }
        offsets[NG] = acc;
    }
    __syncthreads();
    if (tid < NG) hist[tid] = base[tid];  // reuse as cursors
    __syncthreads();
#pragma unroll
    for (int i = 0; i < 4; i++) {
        int pos = atomicAdd(&hist[g[i]], 1);
        row_ids[pos] = tid + i * 1024;
    }
}

// ---------------------------------------------------------------------------
// fused transpose + fp32->bf16: in [R][1024] fp32 -> out [1024][R] bf16.
// 64x64 tiles, 256 thr. Round-7 rewrite: old version was 2B-scalar-store
// bound (48 us @ 1.87 TB/s). Now: float4 loads -> LDS fp32 tile (16 KB) with
// XOR float4-group swizzle pg = cv ^ (r>>3) (store side linear/conflict-free;
// read side 8 rows x 8 oc covers all 32 banks) -> bf16x8 16B stores, 128B
// contiguous per 8 lanes.
// tiles: Ws1 8x16=128; Ws2 16x16=256; We1 10*256; We2 10*256 -> 5504 blocks.
// ---------------------------------------------------------------------------
__global__ void transpose_all_kernel(const float* __restrict__ Ws1,
                                     const float* __restrict__ Ws2,
                                     const float* __restrict__ We1,
                                     const float* __restrict__ We2,
                                     bf16* __restrict__ WT1,
                                     bf16* __restrict__ WT2,
                                     bf16* __restrict__ WE1T,
                                     bf16* __restrict__ WE2T) {
    int b = blockIdx.x;
    const float* src;
    bf16* dst;
    int R, ty;
    if (b < 128) {
        src = Ws1; dst = WT1; R = 512; ty = b >> 4; b &= 15;
    } else if (b < 384) {
        b -= 128; src = Ws2; dst = WT2; R = 1024; ty = b >> 4; b &= 15;
    } else if (b < 2944) {
        b -= 384;
        int e = b >> 8; b &= 255;
        src = We1 + (size_t)e * DIM * DIM;
        dst = WE1T + (size_t)e * DIM * DIM;
        R = 1024; ty = b >> 4; b &= 15;
    } else {
        b -= 2944;
        int e = b >> 8; b &= 255;
        src = We2 + (size_t)e * DIM * DIM;
        dst = WE2T + (size_t)e * DIM * DIM;
        R = 1024; ty = b >> 4; b &= 15;
    }
    const int r0 = ty * 64, c0 = b * 64;
    __shared__ float T[64 * 64];
    const int tid = threadIdx.x;
    // load: slot s -> r = s>>4, float4-group cv = s&15, phys pg = cv^(r>>3)
#pragma unroll
    for (int i = 0; i < 4; i++) {
        const int s = i * 256 + tid;
        const int r = s >> 4;
        const int cv = s & 15;
        floatx4 v = *(const floatx4*)(src + (size_t)(r0 + r) * 1024 + c0 + cv * 4);
        *(floatx4*)(T + r * 64 + ((cv ^ (r >> 3)) * 4)) = v;
    }
    __syncthreads();
    // store: slot s -> oc = s>>3 (out-row = col), og = s&7 (octet of out-cols)
#pragma unroll
    for (int i = 0; i < 2; i++) {
        const int s = i * 256 + tid;
        const int oc = s >> 3;
        const int og = s & 7;
        const int cg = oc >> 2, o = oc & 3;
        bf16x8 v;
#pragma unroll
        for (int t = 0; t < 8; t++) {
            const int r = og * 8 + t;
            v[t] = (bf16)T[r * 64 + ((cg ^ (r >> 3)) * 4) + o];
        }
        *(bf16x8*)(dst + (size_t)(c0 + oc) * R + r0 + og * 8) = v;
    }
}

// ---------------------------------------------------------------------------
// GEMM: C = act(A @ BT^T + bias). A [M][K] bf16, BT [N][K] bf16.
// 128M x 64N tile, BK=128 (round-7: Mt 64->128 halves expert-weight re-reads,
// the LLC-BW term pinning GEMMs at ~45 us; MFMA:ds_read 8:6 per ks).
// 4 waves as 2x2 over (128m, 64n): each wave 64m x 32n, acc[4][2].
// m97-style global_load_lds width=16 staging; source-side XOR octet swizzle
// slot s -> (row=s>>4, oct=(s&15)^(row&15)). LDS 48 KB -> 3 blocks/CU.
// EXPERT: grid.z = genre; rows are bucket positions [0,count) at offsets[g].
// ---------------------------------------------------------------------------
template <bool EXPERT, bool GATHER_A, bool SCATTER_C, bool GELU, typename CT>
__global__ __launch_bounds__(256, 4) void gemm_kernel(
    const bf16* __restrict__ A, const bf16* __restrict__ BT,
    const float* __restrict__ bias, CT* __restrict__ Cmat,
    int M, int N, int K,
    const int* __restrict__ row_ids, const int* __restrict__ offsets,
    const int* __restrict__ counts) {
    int off = 0, cnt = M;
    if (EXPERT) {
        const int g = blockIdx.z;
        cnt = counts[g];
        if ((int)blockIdx.y * 128 >= cnt) return;
        off = offsets[g];
        BT += (size_t)g * N * K;
        bias += (size_t)g * N;
    }
    const int m_start = blockIdx.y * 128;
    const int n0 = blockIdx.x * 64;

    constexpr int BK = 128;  // 16 octets per row
    __shared__ bf16 As[128 * BK];
    __shared__ bf16 Bs[64 * BK];

    const int tid = threadIdx.x;
    const int lane = tid & 63;
    const int wave = tid >> 6;
    const int wrow = (wave >> 1) * 64;
    const int wcol = (wave & 1) * 32;
    const int quad = lane >> 4;
    const int l16 = lane & 15;

    // A staging: 2048 slots (128 rows x 16 octets), 8 issues
    const bf16* a_src[8];
    bf16* a_dst[8];
#pragma unroll
    for (int i = 0; i < 8; i++) {
        const int s = i * 256 + tid;
        const int row = s >> 4;
        const int col = ((s & 15) ^ (row & 15)) * 8;
        a_dst[i] = As + (i * 256 + wave * 64) * 8;  // wave-uniform; +lane*16 HW
        int p = m_start + row;
        size_t arow;
        if (EXPERT) {
            int pp = off + min(p, cnt - 1);
            arow = GATHER_A ? (size_t)row_ids[pp] : (size_t)pp;
        } else {
            arow = (size_t)p;
        }
        a_src[i] = A + arow * (size_t)K + col;
    }
    // B staging: 1024 slots (64 rows x 16 octets), 4 issues
    const bf16* b_src[4];
    bf16* b_dst[4];
#pragma unroll
    for (int i = 0; i < 4; i++) {
        const int s = i * 256 + tid;
        const int row = s >> 4;
        const int col = ((s & 15) ^ (row & 15)) * 8;
        b_dst[i] = Bs + (i * 256 + wave * 64) * 8;
        b_src[i] = BT + (size_t)(n0 + row) * K + col;
    }

    floatx4 acc[4][2];
#pragma unroll
    for (int i = 0; i < 4; i++)
#pragma unroll
        for (int j = 0; j < 2; j++)
#pragma unroll
            for (int r = 0; r < 4; r++) acc[i][j][r] = 0.0f;

    const int nK = K / BK;
    for (int kt = 0; kt < nK; kt++) {
        const int kbase = kt * BK;
#pragma unroll
        for (int i = 0; i < 8; i++) async16(a_dst[i], a_src[i] + kbase);
#pragma unroll
        for (int i = 0; i < 4; i++) async16(b_dst[i], b_src[i] + kbase);
        __syncthreads();
#pragma unroll
        for (int ks = 0; ks < 4; ks++) {
            bf16x8 af[4], bfr[2];
            const int cb = ks * 4 + quad;
#pragma unroll
            for (int i = 0; i < 4; i++) {
                const int r = wrow + i * 16 + l16;
                af[i] = *(const bf16x8*)(As + (r * 16 + (cb ^ (r & 15))) * 8);
            }
#pragma unroll
            for (int j = 0; j < 2; j++) {
                const int n = wcol + j * 16 + l16;
                bfr[j] = *(const bf16x8*)(Bs + (n * 16 + (cb ^ (n & 15))) * 8);
            }
#pragma unroll
            for (int i = 0; i < 4; i++)
#pragma unroll
                for (int j = 0; j < 2; j++)
                    acc[i][j] = __builtin_amdgcn_mfma_f32_16x16x32_bf16(
                        af[i], bfr[j], acc[i][j], 0, 0, 0);
        }
        __syncthreads();
    }

    // epilogue: C/D layout col = lane&15, row = quad*4 + reg  [m89-verified]
#pragma unroll
    for (int j = 0; j < 2; j++) {
        const int n = n0 + wcol + j * 16 + l16;
        const float bv = bias[n];
#pragma unroll
        for (int i = 0; i < 4; i++) {
            const int rbase = wrow + i * 16 + quad * 4;
#pragma unroll
            for (int r = 0; r < 4; r++) {
                const int p = m_start + rbase + r;
                if (EXPERT && p >= cnt) continue;
                float v = acc[i][j][r] + bv;
                if (GELU) v = geluf(v);
                size_t drow;
                if (EXPERT) {
                    const int pp = off + p;
                    drow = SCATTER_C ? (size_t)row_ids[pp] : (size_t)pp;
                } else {
                    drow = (size_t)p;
                }
                Cmat[drow * (size_t)N + n] = (CT)v;
            }
        }
    }
}

extern "C" void kernel_launch(void* const* d_in, const int* in_sizes, int n_in,
                              void* d_out, int out_size, void* d_ws,
                              size_t ws_size, hipStream_t stream) {
    // 0 noise (unused), 1 genre(i32), 2 z, 3 mu_table, 4 sigma_table,
    // 5 Ws1, 6 bs1, 7 Ws2, 8 bs2, 9 We1, 10 be1, 11 We2, 12 be2  (all fp32)
    const int* genre = (const int*)d_in[1];
    const float* z = (const float*)d_in[2];
    const float* mu_t = (const float*)d_in[3];
    const float* sg_t = (const float*)d_in[4];
    const float* Ws1 = (const float*)d_in[5];
    const float* bs1 = (const float*)d_in[6];
    const float* Ws2 = (const float*)d_in[7];
    const float* bs2 = (const float*)d_in[8];
    const float* We1 = (const float*)d_in[9];
    const float* be1 = (const float*)d_in[10];
    const float* We2 = (const float*)d_in[11];
    const float* be2 = (const float*)d_in[12];
    float* out = (float*)d_out;

    // Workspace (~63.1 MB): ints first, weights last.
    char* w = (char*)d_ws;
    int* counts = (int*)w;
    int* offsets = (int*)(w + 256);
    int* row_ids = (int*)(w + 1024);
    char* wb = w + (64 << 10);
    bf16* ng = (bf16*)wb;
    bf16* hp = (bf16*)wb;
    bf16* s1 = (bf16*)(wb + ((size_t)4 << 20));
    bf16* s2 = (bf16*)(wb + ((size_t)12 << 20));
    bf16* WT1 = (bf16*)(wb + ((size_t)20 << 20));
    bf16* WT2 = WT1 + (size_t)IN_DIM * DIM;
    bf16* WE1T = WT2 + (size_t)DIM * DIM;
    bf16* WE2T = WE1T + (size_t)NG * DIM * DIM;

    bucket_kernel<<<1, 1024, 0, stream>>>(genre, counts, offsets, row_ids);
    prep_kernel<<<B_ROWS * IN_DIM / 8 / 256, 256, 0, stream>>>(genre, z, mu_t,
                                                               sg_t, ng);
    transpose_all_kernel<<<5504, 256, 0, stream>>>(Ws1, Ws2, We1, We2, WT1,
                                                   WT2, WE1T, WE2T);

    // shared MLP
    gemm_kernel<false, false, false, true, bf16>
        <<<dim3(DIM / 64, B_ROWS / 128), 256, 0, stream>>>(
            ng, WT1, bs1, s1, B_ROWS, DIM, IN_DIM, nullptr, nullptr, nullptr);
    gemm_kernel<false, false, false, true, bf16>
        <<<dim3(DIM / 64, B_ROWS / 128), 256, 0, stream>>>(
            s1, WT2, bs2, s2, B_ROWS, DIM, DIM, nullptr, nullptr, nullptr);
    // expert layer 1: gather rows by bucket, gelu, write permuted h
    gemm_kernel<true, true, false, true, bf16>
        <<<dim3(DIM / 64, B_ROWS / 128, NG), 256, 0, stream>>>(
            s2, WE1T, be1, hp, B_ROWS, DIM, DIM, row_ids, offsets, counts);
    // expert layer 2: contiguous permuted h, scatter rows to fp32 out
    gemm_kernel<true, false, true, false, float>
        <<<dim3(DIM / 64, B_ROWS / 128, NG), 256, 0, stream>>>(
            hp, WE2T, be2, out, B_ROWS, DIM, DIM, row_ids, offsets, counts);
}

// Round 8
// 250.021 us; speedup vs baseline: 1.5810x; 1.0164x over previous
//
#include <hip/hip_runtime.h>
#include <hip/hip_bf16.h>

typedef __bf16 bf16;
typedef __bf16 bf16x8 __attribute__((ext_vector_type(8)));
typedef float floatx4 __attribute__((ext_vector_type(4)));

#define B_ROWS 4096
#define IN_DIM 512
#define DIM 1024
#define NG 10

__device__ __forceinline__ float geluf(float x) {
    return 0.5f * x * (1.0f + erff(x * 0.70710678118654752f));
}

// async global->LDS, 16B per lane; LDS dest = wave-uniform base + lane*16
__device__ __forceinline__ void async16(void* lds, const void* g) {
    __builtin_amdgcn_global_load_lds(
        (const __attribute__((address_space(1))) unsigned int*)g,
        (__attribute__((address_space(3))) unsigned int*)lds, 16, 0, 0);
}
// s_waitcnt vmcnt(N) only (lgkm=15, exp=7 -> no wait): imm = 0x0F70|N
#define WAIT_VM(N) __builtin_amdgcn_s_waitcnt(0x0F70 | (N))
#define BARRIER() __builtin_amdgcn_s_barrier()

// ---------------------------------------------------------------------------
// prep: ng = bf16( mu[g] + (|sigma[g]|+eps) * z ). Pure elementwise.
// ---------------------------------------------------------------------------
__global__ void prep_kernel(const int* __restrict__ genre,
                            const float* __restrict__ z,
                            const float* __restrict__ mu_t,
                            const float* __restrict__ sg_t,
                            bf16* __restrict__ ng) {
    const int t = blockIdx.x * 256 + threadIdx.x;
    const int row = t >> 6;
    const int c0 = (t & 63) * 8;
    const int g = genre[row];
    const float* zp = z + (size_t)row * IN_DIM + c0;
    const float* mp = mu_t + (size_t)g * IN_DIM + c0;
    const float* sp = sg_t + (size_t)g * IN_DIM + c0;
    floatx4 z0 = *(const floatx4*)zp, z1 = *(const floatx4*)(zp + 4);
    floatx4 m0 = *(const floatx4*)mp, m1 = *(const floatx4*)(mp + 4);
    floatx4 s0 = *(const floatx4*)sp, s1 = *(const floatx4*)(sp + 4);
    bf16x8 o;
#pragma unroll
    for (int i = 0; i < 4; i++) {
        o[i] = (bf16)(m0[i] + (fabsf(s0[i]) + 1e-8f) * z0[i]);
        o[i + 4] = (bf16)(m1[i] + (fabsf(s1[i]) + 1e-8f) * z1[i]);
    }
    *(bf16x8*)(ng + (size_t)row * IN_DIM + c0) = o;
}

// ---------------------------------------------------------------------------
// bucket: histogram + prefix + scatter in ONE block (1024 thr), LDS atomics.
// ---------------------------------------------------------------------------
__global__ void bucket_kernel(const int* __restrict__ genre,
                              int* __restrict__ counts,
                              int* __restrict__ offsets,
                              int* __restrict__ row_ids) {
    __shared__ int hist[NG];
    __shared__ int base[NG];
    const int tid = threadIdx.x;
    if (tid < NG) hist[tid] = 0;
    __syncthreads();
    int g[4];
#pragma unroll
    for (int i = 0; i < 4; i++) {
        g[i] = genre[tid + i * 1024];
        atomicAdd(&hist[g[i]], 1);
    }
    __syncthreads();
    if (tid == 0) {
        int acc = 0;
        for (int e = 0; e < NG; e++) {
            base[e] = acc;
            counts[e] = hist[e];
            offsets[e] = acc;
            acc += hist[e];
        }
        offsets[NG] = acc;
    }
    __syncthreads();
    if (tid < NG) hist[tid] = base[tid];
    __syncthreads();
#pragma unroll
    for (int i = 0; i < 4; i++) {
        int pos = atomicAdd(&hist[g[i]], 1);
        row_ids[pos] = tid + i * 1024;
    }
}

// ---------------------------------------------------------------------------
// fused transpose + fp32->bf16: [R][1024] fp32 -> [1024][R] bf16.
// Round-8: 2 row-adjacent 64x64 tiles per block, 8 loads in flight before a
// single barrier (halves latency exposures). LDS 32 KB -> 5 blocks/CU.
// 2752 blocks: Ws1 64, Ws2 128, We1 1280, We2 1280.
// ---------------------------------------------------------------------------
__global__ void transpose_all_kernel(const float* __restrict__ Ws1,
                                     const float* __restrict__ Ws2,
                                     const float* __restrict__ We1,
                                     const float* __restrict__ We2,
                                     bf16* __restrict__ WT1,
                                     bf16* __restrict__ WT2,
                                     bf16* __restrict__ WE1T,
                                     bf16* __restrict__ WE2T) {
    int b = blockIdx.x;
    const float* src;
    bf16* dst;
    int R;
    if (b < 64) {
        src = Ws1; dst = WT1; R = 512;
    } else if (b < 192) {
        b -= 64; src = Ws2; dst = WT2; R = 1024;
    } else if (b < 1472) {
        b -= 192;
        int e = b >> 7; b &= 127;
        src = We1 + (size_t)e * DIM * DIM;
        dst = WE1T + (size_t)e * DIM * DIM;
        R = 1024;
    } else {
        b -= 1472;
        int e = b >> 7; b &= 127;
        src = We2 + (size_t)e * DIM * DIM;
        dst = WE2T + (size_t)e * DIM * DIM;
        R = 1024;
    }
    const int r0 = (b >> 4) * 128;
    const int c0 = (b & 15) * 64;
    __shared__ float T[2][64 * 64];
    const int tid = threadIdx.x;
#pragma unroll
    for (int t = 0; t < 2; t++)
#pragma unroll
        for (int i = 0; i < 4; i++) {
            const int s = i * 256 + tid;
            const int r = s >> 4;
            const int cv = s & 15;
            floatx4 v = *(const floatx4*)(src + (size_t)(r0 + t * 64 + r) * 1024 +
                                          c0 + cv * 4);
            *(floatx4*)(T[t] + r * 64 + ((cv ^ (r >> 3)) * 4)) = v;
        }
    __syncthreads();
#pragma unroll
    for (int t = 0; t < 2; t++)
#pragma unroll
        for (int i = 0; i < 2; i++) {
            const int s = i * 256 + tid;
            const int oc = s >> 3;
            const int og = s & 7;
            const int cg = oc >> 2, o = oc & 3;
            bf16x8 v;
#pragma unroll
            for (int u = 0; u < 8; u++) {
                const int r = og * 8 + u;
                v[u] = (bf16)T[t][r * 64 + ((cg ^ (r >> 3)) * 4) + o];
            }
            *(bf16x8*)(dst + (size_t)(c0 + oc) * R + r0 + t * 64 + og * 8) = v;
        }
}

// ---------------------------------------------------------------------------
// GEMM: C = act(A @ BT^T + bias). A [M][K] bf16, BT [N][K] bf16.
// 128M x 64N tile, BK=64, DOUBLE-BUFFERED async staging (round-8): per iter
// issue 6 global_load_lds into nxt, s_waitcnt vmcnt(6) (waits only cur's 6),
// raw s_barrier, compute cur, raw s_barrier. No vmcnt(0) drain in the loop —
// the round-7 structure exposed a full load latency per iter (MfmaUtil 5%).
// LDS 2x(16+8) KB = 48 KB -> 3 blocks/CU. Source-side XOR octet swizzle
// slot s -> (row=s>>3, oct=(s&7)^(row&7)); fragment ds_read_b128 2-way max.
// EXPERT: grid.z = genre; rows are bucket positions [0,count) at offsets[g].
// ---------------------------------------------------------------------------
template <bool EXPERT, bool GATHER_A, bool SCATTER_C, bool GELU, typename CT>
__global__ __launch_bounds__(256, 3) void gemm_kernel(
    const bf16* __restrict__ A, const bf16* __restrict__ BT,
    const float* __restrict__ bias, CT* __restrict__ Cmat,
    int M, int N, int K,
    const int* __restrict__ row_ids, const int* __restrict__ offsets,
    const int* __restrict__ counts) {
    int off = 0, cnt = M;
    if (EXPERT) {
        const int g = blockIdx.z;
        cnt = counts[g];
        if ((int)blockIdx.y * 128 >= cnt) return;
        off = offsets[g];
        BT += (size_t)g * N * K;
        bias += (size_t)g * N;
    }
    const int m_start = blockIdx.y * 128;
    const int n0 = blockIdx.x * 64;

    constexpr int BK = 64;  // 8 octets per row
    __shared__ bf16 As[2][128 * BK];
    __shared__ bf16 Bs[2][64 * BK];

    const int tid = threadIdx.x;
    const int lane = tid & 63;
    const int wave = tid >> 6;
    const int wrow = (wave >> 1) * 64;
    const int wcol = (wave & 1) * 32;
    const int quad = lane >> 4;
    const int l16 = lane & 15;

    // A staging: 1024 slots (128 rows x 8 octets), 4 issues of 256
    const bf16* a_src[4];
#pragma unroll
    for (int i = 0; i < 4; i++) {
        const int s = i * 256 + tid;
        const int row = s >> 3;
        const int col = ((s & 7) ^ (row & 7)) * 8;
        int p = m_start + row;
        size_t arow;
        if (EXPERT) {
            int pp = off + min(p, cnt - 1);
            arow = GATHER_A ? (size_t)row_ids[pp] : (size_t)pp;
        } else {
            arow = (size_t)p;
        }
        a_src[i] = A + arow * (size_t)K + col;
    }
    // B staging: 512 slots (64 rows x 8 octets), 2 issues
    const bf16* b_src[2];
#pragma unroll
    for (int i = 0; i < 2; i++) {
        const int s = i * 256 + tid;
        const int row = s >> 3;
        const int col = ((s & 7) ^ (row & 7)) * 8;
        b_src[i] = BT + (size_t)(n0 + row) * K + col;
    }
    const int ldsbase = wave * 64 * 8;  // wave-uniform; HW adds lane*16

    floatx4 acc[4][2];
#pragma unroll
    for (int i = 0; i < 4; i++)
#pragma unroll
        for (int j = 0; j < 2; j++)
#pragma unroll
            for (int r = 0; r < 4; r++) acc[i][j][r] = 0.0f;

    const int nK = K / BK;
    // prologue: k=0 into buf0
#pragma unroll
    for (int i = 0; i < 4; i++) async16(&As[0][i * 2048 + ldsbase], a_src[i]);
#pragma unroll
    for (int i = 0; i < 2; i++) async16(&Bs[0][i * 2048 + ldsbase], b_src[i]);

    for (int kt = 0; kt < nK; kt++) {
        const int cur = kt & 1, nxt = cur ^ 1;
        const int kn = (kt + 1 < nK) ? (kt + 1) * BK : 0;  // clamp: harmless
#pragma unroll
        for (int i = 0; i < 4; i++)
            async16(&As[nxt][i * 2048 + ldsbase], a_src[i] + kn);
#pragma unroll
        for (int i = 0; i < 2; i++)
            async16(&Bs[nxt][i * 2048 + ldsbase], b_src[i] + kn);
        WAIT_VM(6);   // cur's 6 loads done; nxt's 6 still in flight
        BARRIER();
#pragma unroll
        for (int ks = 0; ks < 2; ks++) {
            bf16x8 af[4], bfr[2];
            const int cb = ks * 4 + quad;
#pragma unroll
            for (int i = 0; i < 4; i++) {
                const int r = wrow + i * 16 + l16;
                af[i] = *(const bf16x8*)(&As[cur][(r * 8 + (cb ^ (r & 7))) * 8]);
            }
#pragma unroll
            for (int j = 0; j < 2; j++) {
                const int n = wcol + j * 16 + l16;
                bfr[j] = *(const bf16x8*)(&Bs[cur][(n * 8 + (cb ^ (n & 7))) * 8]);
            }
#pragma unroll
            for (int i = 0; i < 4; i++)
#pragma unroll
                for (int j = 0; j < 2; j++)
                    acc[i][j] = __builtin_amdgcn_mfma_f32_16x16x32_bf16(
                        af[i], bfr[j], acc[i][j], 0, 0, 0);
        }
        BARRIER();  // protect cur before next iter overwrites it
    }

    // epilogue: C/D layout col = lane&15, row = quad*4 + reg  [m89-verified]
#pragma unroll
    for (int j = 0; j < 2; j++) {
        const int n = n0 + wcol + j * 16 + l16;
        const float bv = bias[n];
#pragma unroll
        for (int i = 0; i < 4; i++) {
            const int rbase = wrow + i * 16 + quad * 4;
#pragma unroll
            for (int r = 0; r < 4; r++) {
                const int p = m_start + rbase + r;
                if (EXPERT && p >= cnt) continue;
                float v = acc[i][j][r] + bv;
                if (GELU) v = geluf(v);
                size_t drow;
                if (EXPERT) {
                    const int pp = off + p;
                    drow = SCATTER_C ? (size_t)row_ids[pp] : (size_t)pp;
                } else {
                    drow = (size_t)p;
                }
                Cmat[drow * (size_t)N + n] = (CT)v;
            }
        }
    }
}

extern "C" void kernel_launch(void* const* d_in, const int* in_sizes, int n_in,
                              void* d_out, int out_size, void* d_ws,
                              size_t ws_size, hipStream_t stream) {
    const int* genre = (const int*)d_in[1];
    const float* z = (const float*)d_in[2];
    const float* mu_t = (const float*)d_in[3];
    const float* sg_t = (const float*)d_in[4];
    const float* Ws1 = (const float*)d_in[5];
    const float* bs1 = (const float*)d_in[6];
    const float* Ws2 = (const float*)d_in[7];
    const float* bs2 = (const float*)d_in[8];
    const float* We1 = (const float*)d_in[9];
    const float* be1 = (const float*)d_in[10];
    const float* We2 = (const float*)d_in[11];
    const float* be2 = (const float*)d_in[12];
    float* out = (float*)d_out;

    // Workspace (~63.1 MB): ints first, weights last.
    char* w = (char*)d_ws;
    int* counts = (int*)w;
    int* offsets = (int*)(w + 256);
    int* row_ids = (int*)(w + 1024);
    char* wb = w + (64 << 10);
    bf16* ng = (bf16*)wb;
    bf16* hp = (bf16*)wb;
    bf16* s1 = (bf16*)(wb + ((size_t)4 << 20));
    bf16* s2 = (bf16*)(wb + ((size_t)12 << 20));
    bf16* WT1 = (bf16*)(wb + ((size_t)20 << 20));
    bf16* WT2 = WT1 + (size_t)IN_DIM * DIM;
    bf16* WE1T = WT2 + (size_t)DIM * DIM;
    bf16* WE2T = WE1T + (size_t)NG * DIM * DIM;

    bucket_kernel<<<1, 1024, 0, stream>>>(genre, counts, offsets, row_ids);
    prep_kernel<<<1024, 256, 0, stream>>>(genre, z, mu_t, sg_t, ng);
    transpose_all_kernel<<<2752, 256, 0, stream>>>(Ws1, Ws2, We1, We2, WT1,
                                                   WT2, WE1T, WE2T);

    // shared MLP
    gemm_kernel<false, false, false, true, bf16>
        <<<dim3(DIM / 64, B_ROWS / 128), 256, 0, stream>>>(
            ng, WT1, bs1, s1, B_ROWS, DIM, IN_DIM, nullptr, nullptr, nullptr);
    gemm_kernel<false, false, false, true, bf16>
        <<<dim3(DIM / 64, B_ROWS / 128), 256, 0, stream>>>(
            s1, WT2, bs2, s2, B_ROWS, DIM, DIM, nullptr, nullptr, nullptr);
    // expert layer 1: gather rows by bucket, gelu, write permuted h
    gemm_kernel<true, true, false, true, bf16>
        <<<dim3(DIM / 64, B_ROWS / 128, NG), 256, 0, stream>>>(
            s2, WE1T, be1, hp, B_ROWS, DIM, DIM, row_ids, offsets, counts);
    // expert layer 2: contiguous permuted h, scatter rows to fp32 out
    gemm_kernel<true, false, true, false, float>
        <<<dim3(DIM / 64, B_ROWS / 128, NG), 256, 0, stream>>>(
            hp, WE2T, be2, out, B_ROWS, DIM, DIM, row_ids, offsets, counts);
}